// Round 11
// baseline (327.773 us; speedup 1.0000x reference)
//
#include <hip/hip_runtime.h>

#define D 256
#define B 128
#define S 64
#define L 32
#define K 32
#define KH 16
#define NW 8      // waves per recurrence block (512 threads), 32 cols/wave
#define NSUB 2    // 16-col sub-tiles per wave
#define HSTR 260  // u16 stride (proven 0-conflict R7/R8)

typedef _Float16 f16x8 __attribute__((ext_vector_type(8)));  // 8 f16 in 4 VGPRs
typedef float f32x4 __attribute__((ext_vector_type(4)));
typedef unsigned short u16;

__device__ __forceinline__ u16 h_bits(_Float16 h) {
    union { _Float16 h; u16 u; } x; x.h = h; return x.u;
}

// ---------------------------------------------------------------------------
// sent_mask extraction, robust to bool shipped as 1-byte or int32.
// ---------------------------------------------------------------------------
__global__ void mask_kernel(const void* mraw, int* mask_out) {
    __shared__ int flag;
    const int tid = threadIdx.x;
    if (tid == 0) flag = 0;
    __syncthreads();
    const unsigned int* w32 = (const unsigned int*)mraw;
    int loc = 0;
    for (int i = tid; i < 1024; i += 256)
        if (w32[i] > 1u) loc = 1;
    if (loc) flag = 1;   // benign race
    __syncthreads();
    const bool is_bytes = (flag != 0);
    const unsigned char* b8 = (const unsigned char*)mraw;
    const int* i32 = (const int*)mraw;
    for (int i = tid; i < B * S; i += 256)
        mask_out[i] = is_bytes ? (int)b8[(size_t)i * L] : i32[(size_t)i * L];
}

// ---------------------------------------------------------------------------
// Fused preprocessing, 2176 blocks:
//  blocks [0,2048):  4 sentences each -> embed gather (into LDS + enc),
//                    eW = enc @ W (1 row x 4 cols per thread),
//                    ek[s,k] = enc[s,:].keys[b,k,:]  (threads 0-127).
//  blocks [2048,2176): keysV = keys[b] @ V (the proven 32-row gemm body).
// Wide grid keeps the gather latency-hidden (R8's 256-block fusion regressed)
// and keysV no longer runs on a half-idle device; 6 launches -> 3.
// ---------------------------------------------------------------------------
__global__ __launch_bounds__(256) void prep_kernel(
    const int* __restrict__ prgrph, const float* __restrict__ E,
    const float* __restrict__ W, const float* __restrict__ keys,
    const float* __restrict__ V,
    float* __restrict__ enc, float* __restrict__ eW,
    float* __restrict__ ek, float* __restrict__ keysV) {
    __shared__ float smem[32 * D];       // 32 KB, shared by both roles
    const int blk = blockIdx.x;
    const int t = threadIdx.x;

    if (blk < (B * S) / 4) {
        // ---------------- sentence role: 4 sentences ----------------
        float (*a_s)[D] = (float (*)[D])smem;          // [4][256]
        __shared__ int sidx[4][L];
        const int bs0 = blk * 4;
        if (t < 4 * L) sidx[t >> 5][t & 31] = prgrph[(size_t)bs0 * L + t];
        __syncthreads();

        const int g = t >> 6, c4 = t & 63;
        const float4* E4 = (const float4*)E;
        float4 a = make_float4(0.f, 0.f, 0.f, 0.f);
        #pragma unroll
        for (int l = 0; l < L; ++l) {
            const float4 v = E4[(size_t)sidx[g][l] * (D / 4) + c4];
            a.x += v.x; a.y += v.y; a.z += v.z; a.w += v.w;
        }
        *(float4*)&a_s[g][c4 * 4] = a;
        *(float4*)&enc[(size_t)(bs0 + g) * D + c4 * 4] = a;
        __syncthreads();

        // eW: row g, cols [4*c4, 4*c4+4)
        const int c0 = c4 * 4;
        float4 acc = make_float4(0.f, 0.f, 0.f, 0.f);
        for (int d = 0; d < D; d += 4) {
            const float4 av = *(const float4*)&a_s[g][d];
            #pragma unroll
            for (int j = 0; j < 4; ++j) {
                const float4 w = *(const float4*)(W + (size_t)(d + j) * D + c0);
                const float aa = (j == 0) ? av.x : (j == 1) ? av.y
                               : (j == 2) ? av.z : av.w;
                acc.x += aa * w.x; acc.y += aa * w.y;
                acc.z += aa * w.z; acc.w += aa * w.w;
            }
        }
        *(float4*)&eW[(size_t)(bs0 + g) * D + c0] = acc;

        // ek: threads 0..127 -> (s = t>>5, k = t&31), full-D dot
        if (t < 128) {
            const int s = t >> 5, k = t & 31;
            const int b = bs0 >> 6;                 // bs0 = b*S + s0
            const float4* kr = (const float4*)(keys + ((size_t)b * K + k) * D);
            const float4* ar = (const float4*)&a_s[s][0];
            float e = 0.f;
            for (int d4 = 0; d4 < D / 4; ++d4) {
                const float4 kv = kr[d4];
                const float4 av = ar[d4];
                e += av.x * kv.x + av.y * kv.y + av.z * kv.z + av.w * kv.w;
            }
            ek[(size_t)(bs0 + s) * K + k] = e;
        }
    } else {
        // ---------------- keysV role: one b, 32 rows ----------------
        const int b = blk - (B * S) / 4;
        const int wave = t >> 6, lane = t & 63;
        float* a_s = smem;
        const float4* Ag = (const float4*)(keys + (size_t)b * K * D);
        float4* As4 = (float4*)a_s;
        for (int i = t; i < K * D / 4; i += 256) As4[i] = Ag[i];
        __syncthreads();
        const int r0 = wave * 8, c0 = lane * 4;
        float4 acc[8];
        #pragma unroll
        for (int i = 0; i < 8; ++i) acc[i] = make_float4(0.f, 0.f, 0.f, 0.f);
        for (int d = 0; d < D; d += 4) {
            float4 av[8];
            #pragma unroll
            for (int i = 0; i < 8; ++i) av[i] = *(const float4*)&a_s[(r0 + i) * D + d];
            #pragma unroll
            for (int j = 0; j < 4; ++j) {
                const float4 w = *(const float4*)(V + (size_t)(d + j) * D + c0);
                #pragma unroll
                for (int i = 0; i < 8; ++i) {
                    const float a = (j == 0) ? av[i].x : (j == 1) ? av[i].y
                                  : (j == 2) ? av[i].z : av[i].w;
                    acc[i].x += a * w.x; acc[i].y += a * w.y;
                    acc[i].z += a * w.z; acc[i].w += a * w.w;
                }
            }
        }
        #pragma unroll
        for (int i = 0; i < 8; ++i)
            *(float4*)&keysV[((size_t)b * K + r0 + i) * D + c0] = acc[i];
    }
}

// ---------------------------------------------------------------------------
// Recurrence — BYTE-IDENTICAL structure to R10 (112 us, no spill, proven).
// Block = (b, 16-row half of K); 512 threads = 8 waves; wave w owns cols
// [32w,32w+32). U f16 hi/lo frags = 128 AGPRs/wave (asm "+a" pin); VGPR ~110
// -> __launch_bounds__(512,2) = 2 blocks/CU, all 512 blocks in ONE round.
// ---------------------------------------------------------------------------
__global__ __launch_bounds__(512, 2) void recur_kernel(
    const float* __restrict__ enc, const float* __restrict__ eWp,
    const float* __restrict__ keysV, const float* __restrict__ ek,
    const float* __restrict__ U, const int* __restrict__ mask,
    float* __restrict__ out) {
    const int b  = blockIdx.x >> 1;
    const int kh = (blockIdx.x & 1) * KH;
    const int t = threadIdx.x;
    const int wave = t >> 6, lane = t & 63;
    const int n = lane & 15, quad = lane >> 4;

    __shared__ u16 hF[2][KH][HSTR];      // 2 x 8.1 KB, f16 h planes
    __shared__ float redN[2][KH][NW];
    __shared__ float redG[2][KH][NW];

    // ---- preload U B-fragments (f16 hi/lo): 2 subs x 8 kt -> 128 AGPRs ----
    f16x8 Uhi[NSUB][8], Ulo[NSUB][8];
    #pragma unroll
    for (int sub = 0; sub < NSUB; ++sub) {
        const int col = wave * 32 + sub * 16 + n;
        #pragma unroll
        for (int kt = 0; kt < 8; ++kt) {
            #pragma unroll
            for (int j = 0; j < 8; ++j) {
                const int k = kt * 32 + quad * 8 + j;
                const float u = U[(size_t)k * D + col];
                const _Float16 uh = (_Float16)u;
                Uhi[sub][kt][j] = uh;
                Ulo[sub][kt][j] = (_Float16)(u - (float)uh);
            }
        }
    }
    #pragma unroll
    for (int sub = 0; sub < NSUB; ++sub)
        #pragma unroll
        for (int kt = 0; kt < 8; ++kt)
            asm volatile("" : "+a"(Uhi[sub][kt]), "+a"(Ulo[sub][kt]));

    // ---- per-lane state ----
    float upv[4][NSUB];
    float rn[4];
    float keysVc[4][NSUB];
    #pragma unroll
    for (int reg = 0; reg < 4; ++reg) {
        rn[reg] = 1.f;
        const size_t base = (size_t)(b * K + kh + quad * 4 + reg) * D;
        #pragma unroll
        for (int sub = 0; sub < NSUB; ++sub) {
            upv[reg][sub] = 0.f;
            keysVc[reg][sub] = keysV[base + wave * 32 + sub * 16 + n];
        }
    }

    const int* bm = mask + b * S;
    unsigned long long rem = __ballot(bm[lane & 63] != 0);

    float eWc[NSUB];
    float4 ekv = make_float4(0.f, 0.f, 0.f, 0.f);
    #pragma unroll
    for (int sub = 0; sub < NSUB; ++sub) eWc[sub] = 0.f;
    if (rem) {
        const int s0 = (int)__builtin_ctzll(rem);
        const size_t eo = (size_t)(b * S + s0) * D;
        #pragma unroll
        for (int sub = 0; sub < NSUB; ++sub)
            eWc[sub] = eWp[eo + wave * 32 + sub * 16 + n];
        ekv = *(const float4*)(ek + (size_t)(b * S + s0) * K + kh + quad * 4);
    }

    int p = 0, q = 0;
    bool first = true;
    while (rem) {
        rem &= rem - 1;
        const int sn = rem ? (int)__builtin_ctzll(rem) : -1;

        // ---- issue next-step e load early (covered by MFMA) ----
        float e_n[NSUB];
        #pragma unroll
        for (int sub = 0; sub < NSUB; ++sub) e_n[sub] = 0.f;
        if (sn >= 0) {
            const size_t eo = (size_t)(b * S + sn) * D;
            #pragma unroll
            for (int sub = 0; sub < NSUB; ++sub)
                e_n[sub] = enc[eo + wave * 32 + sub * 16 + n];
        }

        // ---- MFMA: acc = h_prev @ (Uhi,Ulo), 4 indep chains of 8 ----
        f32x4 acc[NSUB][2];
        #pragma unroll
        for (int sub = 0; sub < NSUB; ++sub) {
            acc[sub][0] = (f32x4){0.f, 0.f, 0.f, 0.f};
            acc[sub][1] = (f32x4){0.f, 0.f, 0.f, 0.f};
        }
        if (!first) {
            #pragma unroll
            for (int kt = 0; kt < 8; ++kt) {
                const f16x8 av = *(const f16x8*)&hF[p][n][kt * 32 + quad * 8];
                #pragma unroll
                for (int sub = 0; sub < NSUB; ++sub) {
                    acc[sub][0] = __builtin_amdgcn_mfma_f32_16x16x32_f16(av, Uhi[sub][kt], acc[sub][0], 0, 0, 0);
                    acc[sub][1] = __builtin_amdgcn_mfma_f32_16x16x32_f16(av, Ulo[sub][kt], acc[sub][1], 0, 0, 0);
                }
            }
        }

        // ---- gate ----
        float gate[4];
        #pragma unroll
        for (int reg = 0; reg < 4; ++reg) {
            const float ekb = (reg == 0) ? ekv.x : (reg == 1) ? ekv.y
                            : (reg == 2) ? ekv.z : ekv.w;
            float g = ekb;
            if (!first) {
                const float* rg = redG[q ^ 1][quad * 4 + reg];
                const float4 g0 = *(const float4*)rg;
                const float4 g1 = *(const float4*)(rg + 4);
                g += rn[reg] * (g0.x + g0.y + g0.z + g0.w +
                                g1.x + g1.y + g1.z + g1.w);
            }
            gate[reg] = 1.f / (1.f + __expf(-g));
        }

        // ---- update + f16 h write + norm/gate-dot partials ----
        const int pw = p ^ 1;
        float pn[4], gd[4];
        #pragma unroll
        for (int reg = 0; reg < 4; ++reg) {
            const int row = quad * 4 + reg;
            float sq = 0.f, dv = 0.f;
            #pragma unroll
            for (int sub = 0; sub < NSUB; ++sub) {
                const float asum = acc[sub][0][reg] + acc[sub][1][reg];
                float ht = rn[reg] * asum + keysVc[reg][sub] + eWc[sub];
                ht = fmaxf(ht, 0.f);
                const float u2 = rn[reg] * upv[reg][sub] + gate[reg] * ht;
                upv[reg][sub] = u2;
                sq += u2 * u2;
                dv += u2 * e_n[sub];
                hF[pw][row][wave * 32 + sub * 16 + n] = h_bits((_Float16)u2);
            }
            pn[reg] = sq;
            gd[reg] = dv;
        }

        // ---- reload step-invariants IN PLACE (last use passed) ----
        if (sn >= 0) {
            const size_t eo = (size_t)(b * S + sn) * D;
            #pragma unroll
            for (int sub = 0; sub < NSUB; ++sub)
                eWc[sub] = eWp[eo + wave * 32 + sub * 16 + n];
            ekv = *(const float4*)(ek + (size_t)(b * S + sn) * K + kh + quad * 4);
        }

        #pragma unroll
        for (int m = 1; m <= 8; m <<= 1) {
            #pragma unroll
            for (int reg = 0; reg < 4; ++reg) {
                pn[reg] += __shfl_xor(pn[reg], m);
                gd[reg] += __shfl_xor(gd[reg], m);
            }
        }
        if (n == 0) {
            #pragma unroll
            for (int reg = 0; reg < 4; ++reg) {
                redN[q][quad * 4 + reg][wave] = pn[reg];
                redG[q][quad * 4 + reg][wave] = gd[reg];
            }
        }

        __syncthreads();   // the ONLY barrier

        #pragma unroll
        for (int reg = 0; reg < 4; ++reg) {
            const float* rp = redN[q][quad * 4 + reg];
            const float4 r0 = *(const float4*)rp;
            const float4 r1 = *(const float4*)(rp + 4);
            rn[reg] = rsqrtf(fmaxf(r0.x + r0.y + r0.z + r0.w +
                                   r1.x + r1.y + r1.z + r1.w, 1e-12f));
        }
        p ^= 1; q ^= 1; first = false;
    }

    #pragma unroll
    for (int reg = 0; reg < 4; ++reg) {
        const size_t base = (size_t)(b * K + kh + quad * 4 + reg) * D;
        #pragma unroll
        for (int sub = 0; sub < NSUB; ++sub)
            out[base + wave * 32 + sub * 16 + n] = rn[reg] * upv[reg][sub];
    }
}

extern "C" void kernel_launch(void* const* d_in, const int* in_sizes, int n_in,
                              void* d_out, int out_size, void* d_ws, size_t ws_size,
                              hipStream_t stream) {
    const int*   prgrph = (const int*)d_in[0];
    const void*  pmask  = d_in[1];
    const float* keys   = (const float*)d_in[2];
    const float* E      = (const float*)d_in[3];
    const float* U      = (const float*)d_in[4];
    const float* V      = (const float*)d_in[5];
    const float* W      = (const float*)d_in[6];
    float* out = (float*)d_out;

    float* ws_enc   = (float*)d_ws;                          // B*S*D  (8 MB)
    float* ws_eW    = ws_enc + (size_t)B * S * D;            // B*S*D  (8 MB)
    float* ws_keysV = ws_eW  + (size_t)B * S * D;            // B*K*D  (4 MB)
    float* ws_ek    = ws_keysV + (size_t)B * K * D;          // B*S*K  (1 MB)
    int*   ws_mask  = (int*)(ws_ek + (size_t)B * S * K);     // B*S

    mask_kernel<<<1, 256, 0, stream>>>(pmask, ws_mask);
    prep_kernel<<<(B * S) / 4 + B, 256, 0, stream>>>(
        prgrph, E, W, keys, V, ws_enc, ws_eW, ws_ek, ws_keysV);
    recur_kernel<<<B * (K / KH), 512, 0, stream>>>(
        ws_enc, ws_eW, ws_keysV, ws_ek, U, ws_mask, out);
}